// Round 1
// baseline (311.964 us; speedup 1.0000x reference)
//
#include <hip/hip_runtime.h>
#include <math.h>

// Problem constants (fixed by reference)
#define NF 8
#define NK 16
#define BB 32
#define YY 32
#define XX 32
#define PP 16
#define TT 8
#define YX (YY*XX)     // 1024
#define PT (PP*TT)     // 128
#define YXPT (YX*PT)   // 131072

// Workspace layout (float offsets)
#define WPT_OFF   0                         // [NF][NK][PT]      = 16384
#define WYX_OFF   16384                     // [NF][YX][NK]      = 131072
#define QMEAN_OFF (WYX_OFF + NF*YX*NK)      // [YXPT]            = 131072
#define ACC_OFF   (QMEAN_OFF + YXPT)        // [BB*NF*NK]        = 4096
#define INTG_OFF  (ACC_OFF + BB*NF*NK)      // [NF*NK]           = 128

// ---------------------------------------------------------------------------
// K1: qmean over b (blocks 0..511), weight tables + zero acc (block 512)
// ---------------------------------------------------------------------------
__global__ void k_prep(const float* __restrict__ quad,
                       const float* __restrict__ mean_lat, const float* __restrict__ logstd_lat,
                       const float* __restrict__ mean_lon, const float* __restrict__ logstd_lon,
                       const float* __restrict__ mean_lev, const float* __restrict__ logstd_lev,
                       const float* __restrict__ logtau,
                       float* __restrict__ ws) {
    const int tid = threadIdx.x;
    if (blockIdx.x < 512) {
        // qmean[j] = mean_b quad[b, j]  (coalesced per-b passes)
        int j = blockIdx.x * 256 + tid;
        float s = 0.f;
        #pragma unroll 4
        for (int b = 0; b < BB; ++b) s += quad[b * YXPT + j];
        ws[QMEAN_OFF + j] = s * (1.0f / BB);
        return;
    }
    // zero the atomic accumulator (ws is re-poisoned 0xAA before every launch)
    for (int i = tid; i < BB * NF * NK; i += 256) ws[ACC_OFF + i] = 0.f;

    // weight tables: thread pair (fk, part) -- 2 threads per (f,k)
    const int fk = tid >> 1;      // 0..127
    const int part = tid & 1;
    const float mlat = mean_lat[fk], slat = expf(logstd_lat[fk]);
    const float mlon = mean_lon[fk], slon = expf(logstd_lon[fk]);
    const float mlev = mean_lev[fk], slev = expf(logstd_lev[fk]);
    const float tau  = expf(logtau[fk]) + 1e-4f;

    // kt[8]
    float ktv[TT];
    #pragma unroll
    for (int t = 0; t < TT; ++t) ktv[t] = expf(-(float)t / tau);
    // wpt[p][t] = kp[p]*kt[t]; part handles 8 of 16 p's
    for (int p = part * 8; p < part * 8 + 8; ++p) {
        float cp = -1.f + 2.f * (float)p / (PP - 1);
        float zp = (cp - mlev) / slev;
        float kp = expf(-0.5f * zp * zp);
        #pragma unroll
        for (int t = 0; t < TT; ++t)
            ws[WPT_OFF + fk * PT + p * TT + t] = kp * ktv[t];
    }
    // kx[32] once
    float kxv[XX];
    #pragma unroll
    for (int x = 0; x < XX; ++x) {
        float cx = -1.f + 2.f * (float)x / (XX - 1);
        float zx = (cx - mlon) / slon;
        kxv[x] = expf(-0.5f * zx * zx);
    }
    const int f = fk >> 4, k = fk & 15;
    // wyx[f][y*XX+x][k] = ky[y]*kx[x]; part handles 16 of 32 y's
    for (int y = part * 16; y < part * 16 + 16; ++y) {
        float cy = -1.f + 2.f * (float)y / (YY - 1);
        float zy = (cy - mlat) / slat;
        float ky = expf(-0.5f * zy * zy);
        for (int x = 0; x < XX; ++x)
            ws[WYX_OFF + (f * YX + y * XX + x) * NK + k] = ky * kxv[x];
    }
}

// ---------------------------------------------------------------------------
// K2: integral[f,k] = sum_{yx,pt} wyx*wpt*qmean + 1e-4   (one block per fk)
// ---------------------------------------------------------------------------
__global__ void k_integral(float* __restrict__ ws) {
    const int fk = blockIdx.x, tid = threadIdx.x;
    const int f = fk >> 4, k = fk & 15;
    const float4* wpt4 = (const float4*)(ws + WPT_OFF + fk * PT);
    float partial = 0.f;
    for (int yx = tid; yx < YX; yx += 256) {
        const float4* qm4 = (const float4*)(ws + QMEAN_OFF + yx * PT);
        float s = 0.f;
        #pragma unroll
        for (int j = 0; j < PT / 4; ++j) {
            float4 w = wpt4[j], q = qm4[j];
            s += w.x * q.x + w.y * q.y + w.z * q.z + w.w * q.w;
        }
        partial += ws[WYX_OFF + (f * YX + yx) * NK + k] * s;
    }
    #pragma unroll
    for (int m = 32; m; m >>= 1) partial += __shfl_xor(partial, m);
    __shared__ float red[4];
    if ((tid & 63) == 0) red[tid >> 6] = partial;
    __syncthreads();
    if (tid == 0) ws[INTG_OFF + fk] = red[0] + red[1] + red[2] + red[3] + 1e-4f;
}

// ---------------------------------------------------------------------------
// K3: main contraction. Block = (b, f, column-chunk of 128). 4 waves/block,
// each wave owns 32 (y,x)-columns, one column per step. lane <-> pt position
// (pt = L and L+64), so the per-(f,k) wpt fragment lives in 32 VGPRs and the
// per-column wyx[16] is a wave-uniform broadcast load.
// ---------------------------------------------------------------------------
__global__ __launch_bounds__(256) void k_main(const float* __restrict__ field,
                                              const float* __restrict__ quad,
                                              float* __restrict__ ws) {
    const int bx = blockIdx.x;
    const int f = bx & 7, chunk = (bx >> 3) & 7, b = bx >> 6;
    const int tid = threadIdx.x;
    const int wave = tid >> 6, L = tid & 63;

    // per-lane wpt fragment: wpt[f][k][L], wpt[f][k][L+64]
    float w0[NK], w1[NK];
    #pragma unroll
    for (int k = 0; k < NK; ++k) {
        const float* p = ws + WPT_OFF + (f * NK + k) * PT;
        w0[k] = p[L];
        w1[k] = p[64 + L];
    }
    float acc[NK];
    #pragma unroll
    for (int k = 0; k < NK; ++k) acc[k] = 0.f;

    const int colBase = chunk * 128 + wave * 32;
    const float* fbase = field + (size_t)(b * NF + f) * YXPT;
    const float* qbase = quad + (size_t)b * YXPT;
    const float* wyxb = ws + WYX_OFF + f * YX * NK;

    #pragma unroll 2
    for (int s = 0; s < 32; ++s) {
        const int c = colBase + s;
        const float* fc = fbase + c * PT;
        const float* qc = qbase + c * PT;
        float f0 = fc[L], f1 = fc[64 + L];
        float q0 = qc[L], q1 = qc[64 + L];
        float g0 = f0 * q0, g1 = f1 * q1;
        // wave-uniform column weights (broadcast loads, L1-resident)
        const float4* wy = (const float4*)(wyxb + c * NK);
        float4 a0 = wy[0], a1 = wy[1], a2 = wy[2], a3 = wy[3];
        float wv[NK];
        *(float4*)(wv + 0)  = a0;
        *(float4*)(wv + 4)  = a1;
        *(float4*)(wv + 8)  = a2;
        *(float4*)(wv + 12) = a3;
        #pragma unroll
        for (int k = 0; k < NK; ++k) {
            float d = fmaf(g1, w1[k], g0 * w0[k]);
            acc[k] = fmaf(wv[k], d, acc[k]);
        }
    }

    // wave butterfly -> cross-wave LDS -> one atomicAdd per (k)
    __shared__ float red[4][NK];
    #pragma unroll
    for (int k = 0; k < NK; ++k) {
        float v = acc[k];
        v += __shfl_xor(v, 32); v += __shfl_xor(v, 16); v += __shfl_xor(v, 8);
        v += __shfl_xor(v, 4);  v += __shfl_xor(v, 2);  v += __shfl_xor(v, 1);
        if (L == 0) red[wave][k] = v;
    }
    __syncthreads();
    if (tid < NK) {
        float s = red[0][tid] + red[1][tid] + red[2][tid] + red[3][tid];
        atomicAdd(ws + ACC_OFF + (b * NF + f) * NK + tid, s);
    }
}

// ---------------------------------------------------------------------------
// K4: out[b,f,k] = acc / integral[f,k]
// ---------------------------------------------------------------------------
__global__ void k_final(const float* __restrict__ ws, float* __restrict__ out) {
    int i = blockIdx.x * 256 + threadIdx.x;
    if (i < BB * NF * NK)
        out[i] = ws[ACC_OFF + i] / ws[INTG_OFF + (i & (NF * NK - 1))];
}

extern "C" void kernel_launch(void* const* d_in, const int* in_sizes, int n_in,
                              void* d_out, int out_size, void* d_ws, size_t ws_size,
                              hipStream_t stream) {
    const float* field = (const float*)d_in[0];
    const float* quad  = (const float*)d_in[1];
    float* ws = (float*)d_ws;

    k_prep<<<513, 256, 0, stream>>>(quad,
        (const float*)d_in[2], (const float*)d_in[3],
        (const float*)d_in[4], (const float*)d_in[5],
        (const float*)d_in[6], (const float*)d_in[7],
        (const float*)d_in[8], ws);
    k_integral<<<NF * NK, 256, 0, stream>>>(ws);
    k_main<<<BB * NF * 8, 256, 0, stream>>>(field, quad, ws);
    k_final<<<(BB * NF * NK + 255) / 256, 256, 0, stream>>>(ws, (float*)d_out);
}

// Round 2
// 268.942 us; speedup vs baseline: 1.1600x; 1.1600x over previous
//
#include <hip/hip_runtime.h>
#include <math.h>

// Problem constants (fixed by reference)
#define NF 8
#define NK 16
#define BB 32
#define YY 32
#define XX 32
#define PP 16
#define TT 8
#define YX (YY*XX)     // 1024
#define PT (PP*TT)     // 128
#define YXPT (YX*PT)   // 131072
#define CHUNKS 8
#define COLS_PER_BLOCK (YX/CHUNKS)       // 128
#define COLS_PER_WAVE  (COLS_PER_BLOCK/4) // 32
#define MAIN_ITERS     (COLS_PER_WAVE/2)  // 16 (2 columns per wave-iter)

// Workspace layout (float offsets)
#define WPT_OFF   0                         // [NF][NK][PT]      = 16384
#define WYX_OFF   (NF*NK*PT)                // [NF][YX][NK]      = 131072
#define QMEAN_OFF (WYX_OFF + NF*YX*NK)      // [YXPT]            = 131072
#define ACC_OFF   (QMEAN_OFF + YXPT)        // [BB*NF*NK]        = 4096
#define INTG_OFF  (ACC_OFF + BB*NF*NK)      // [NF*NK]           = 128

// ---------------------------------------------------------------------------
// K1: blocks 0..511  -> qmean (b-split 4 ways + LDS reduce)
//     blocks 512..639-> weight tables, one block per (f,k)
//     block 640      -> zero acc, seed integral with 1e-4
// ---------------------------------------------------------------------------
__global__ __launch_bounds__(256) void k_prep(const float* __restrict__ quad,
                       const float* __restrict__ mean_lat, const float* __restrict__ logstd_lat,
                       const float* __restrict__ mean_lon, const float* __restrict__ logstd_lon,
                       const float* __restrict__ mean_lev, const float* __restrict__ logstd_lev,
                       const float* __restrict__ logtau,
                       float* __restrict__ ws) {
    const int tid = threadIdx.x, bx = blockIdx.x;

    if (bx < 512) {
        // qmean: block owns 64 float4 columns; 4 b-groups of 8 reduce via LDS
        __shared__ float4 sm[256];
        const int j4 = bx * 64 + (tid & 63);
        const int bg = tid >> 6;
        const float4* q4 = (const float4*)quad;
        float4 a = make_float4(0.f, 0.f, 0.f, 0.f);
        #pragma unroll
        for (int i = 0; i < 8; ++i) {
            float4 v = q4[(size_t)(bg * 8 + i) * (YXPT / 4) + j4];
            a.x += v.x; a.y += v.y; a.z += v.z; a.w += v.w;
        }
        sm[tid] = a;
        __syncthreads();
        if (tid < 64) {
            float4 r0 = sm[tid], r1 = sm[tid + 64], r2 = sm[tid + 128], r3 = sm[tid + 192];
            float4 r;
            r.x = (r0.x + r1.x + r2.x + r3.x) * (1.f / BB);
            r.y = (r0.y + r1.y + r2.y + r3.y) * (1.f / BB);
            r.z = (r0.z + r1.z + r2.z + r3.z) * (1.f / BB);
            r.w = (r0.w + r1.w + r2.w + r3.w) * (1.f / BB);
            ((float4*)(ws + QMEAN_OFF))[j4] = r;
        }
        return;
    }
    if (bx == 640) {
        for (int i = tid; i < BB * NF * NK; i += 256) ws[ACC_OFF + i] = 0.f;
        if (tid < NF * NK) ws[INTG_OFF + tid] = 1e-4f;
        return;
    }
    // weight tables: one block per fk, 128 active threads
    const int fk = bx - 512;
    if (tid >= 128) return;
    const int f = fk >> 4, k = fk & 15;
    const float mlat = mean_lat[fk], slat = expf(logstd_lat[fk]);
    const float mlon = mean_lon[fk], slon = expf(logstd_lon[fk]);
    const float mlev = mean_lev[fk], slev = expf(logstd_lev[fk]);
    const float tau  = expf(logtau[fk]) + 1e-4f;

    // wpt[fk][tid]:  p = tid>>3, t = tid&7  (coalesced store)
    {
        const int p = tid >> 3, t = tid & 7;
        const float cp = -1.f + 2.f * (float)p / (PP - 1);
        const float zp = (cp - mlev) / slev;
        ws[WPT_OFF + fk * PT + tid] = expf(-0.5f * zp * zp) * expf(-(float)t / tau);
    }
    // wyx[f][yx][k]: 8 yx per thread
    #pragma unroll
    for (int i = 0; i < 8; ++i) {
        const int yx = i * 128 + tid;
        const int y = yx >> 5, x = yx & 31;
        const float cy = -1.f + 2.f * (float)y / (YY - 1);
        const float cx = -1.f + 2.f * (float)x / (XX - 1);
        const float zy = (cy - mlat) / slat;
        const float zx = (cx - mlon) / slon;
        ws[WYX_OFF + (f * YX + yx) * NK + k] = expf(-0.5f * zy * zy) * expf(-0.5f * zx * zx);
    }
}

// ---------------------------------------------------------------------------
// K2: integral[f,k] += sum_{yx,pt} wyx*wpt*qmean  (block = (fk, quarter))
// ---------------------------------------------------------------------------
__global__ __launch_bounds__(256) void k_integral(float* __restrict__ ws) {
    const int fk = blockIdx.x >> 2, qr = blockIdx.x & 3;
    const int tid = threadIdx.x;
    const int f = fk >> 4, k = fk & 15;
    const int yx = qr * 256 + tid;
    const float4* w4 = (const float4*)(ws + WPT_OFF + fk * PT);
    const float4* q4 = (const float4*)(ws + QMEAN_OFF + (size_t)yx * PT);
    float s = 0.f;
    #pragma unroll
    for (int j = 0; j < PT / 4; ++j) {
        float4 w = w4[j], q = q4[j];
        s += w.x * q.x + w.y * q.y + w.z * q.z + w.w * q.w;
    }
    float partial = ws[WYX_OFF + (f * YX + yx) * NK + k] * s;
    #pragma unroll
    for (int m = 32; m; m >>= 1) partial += __shfl_xor(partial, m);
    __shared__ float red[4];
    if ((tid & 63) == 0) red[tid >> 6] = partial;
    __syncthreads();
    if (tid == 0) atomicAdd(ws + INTG_OFF + fk, red[0] + red[1] + red[2] + red[3]);
}

// ---------------------------------------------------------------------------
// K3: main contraction. Block = (b, f, chunk of 128 columns); 4 waves/block.
// Lane L loads float4 at offset 4L -> a wave-iter covers 2 full (y,x) columns
// (256 contiguous floats). wpt fragment (float4 per k, by lane quad-group)
// lives in 64 VGPRs; per-column wyx is a 2-address broadcast float4 load.
// ---------------------------------------------------------------------------
__global__ __launch_bounds__(256, 4) void k_main(const float* __restrict__ field,
                                                 const float* __restrict__ quad,
                                                 float* __restrict__ ws) {
    const int bx = blockIdx.x;
    const int f = bx & 7, chunk = (bx >> 3) & 7, b = bx >> 6;
    const int tid = threadIdx.x;
    const int wave = tid >> 6, L = tid & 63;
    const int half = L >> 5, qg = L & 31;   // lane's column half + pt quad-group

    float4 wf[NK];
    #pragma unroll
    for (int k = 0; k < NK; ++k)
        wf[k] = *(const float4*)(ws + WPT_OFF + (f * NK + k) * PT + 4 * qg);

    float acc[NK];
    #pragma unroll
    for (int k = 0; k < NK; ++k) acc[k] = 0.f;

    const int colBase = chunk * COLS_PER_BLOCK + wave * COLS_PER_WAVE;
    const float* fptr = field + (size_t)(b * NF + f) * YXPT + colBase * PT + 4 * L;
    const float* qptr = quad + (size_t)b * YXPT + colBase * PT + 4 * L;
    const float* wyxc = ws + WYX_OFF + (f * YX + colBase + half) * NK;

    #pragma unroll 2
    for (int s = 0; s < MAIN_ITERS; ++s) {
        float4 fv = *(const float4*)(fptr + s * 2 * PT);
        float4 qv = *(const float4*)(qptr + s * 2 * PT);
        const float4* wy = (const float4*)(wyxc + s * 2 * NK);
        float4 a0 = wy[0], a1 = wy[1], a2 = wy[2], a3 = wy[3];
        float wv[NK];
        *(float4*)(wv + 0)  = a0;
        *(float4*)(wv + 4)  = a1;
        *(float4*)(wv + 8)  = a2;
        *(float4*)(wv + 12) = a3;
        float4 g;
        g.x = fv.x * qv.x; g.y = fv.y * qv.y; g.z = fv.z * qv.z; g.w = fv.w * qv.w;
        #pragma unroll
        for (int k = 0; k < NK; ++k) {
            float d = g.x * wf[k].x;
            d = fmaf(g.y, wf[k].y, d);
            d = fmaf(g.z, wf[k].z, d);
            d = fmaf(g.w, wf[k].w, d);
            acc[k] = fmaf(wv[k], d, acc[k]);
        }
    }

    // wave butterfly -> cross-wave LDS -> one atomicAdd per k
    __shared__ float red[4][NK];
    #pragma unroll
    for (int k = 0; k < NK; ++k) {
        float v = acc[k];
        v += __shfl_xor(v, 32); v += __shfl_xor(v, 16); v += __shfl_xor(v, 8);
        v += __shfl_xor(v, 4);  v += __shfl_xor(v, 2);  v += __shfl_xor(v, 1);
        if (L == 0) red[wave][k] = v;
    }
    __syncthreads();
    if (tid < NK) {
        float s2 = red[0][tid] + red[1][tid] + red[2][tid] + red[3][tid];
        atomicAdd(ws + ACC_OFF + (b * NF + f) * NK + tid, s2);
    }
}

// ---------------------------------------------------------------------------
// K4: out[b,f,k] = acc / integral[f,k]
// ---------------------------------------------------------------------------
__global__ void k_final(const float* __restrict__ ws, float* __restrict__ out) {
    int i = blockIdx.x * 256 + threadIdx.x;
    if (i < BB * NF * NK)
        out[i] = ws[ACC_OFF + i] / ws[INTG_OFF + (i & (NF * NK - 1))];
}

extern "C" void kernel_launch(void* const* d_in, const int* in_sizes, int n_in,
                              void* d_out, int out_size, void* d_ws, size_t ws_size,
                              hipStream_t stream) {
    const float* field = (const float*)d_in[0];
    const float* quad  = (const float*)d_in[1];
    float* ws = (float*)d_ws;

    k_prep<<<641, 256, 0, stream>>>(quad,
        (const float*)d_in[2], (const float*)d_in[3],
        (const float*)d_in[4], (const float*)d_in[5],
        (const float*)d_in[6], (const float*)d_in[7],
        (const float*)d_in[8], ws);
    k_integral<<<NF * NK * 4, 256, 0, stream>>>(ws);
    k_main<<<BB * NF * CHUNKS, 256, 0, stream>>>(field, quad, ws);
    k_final<<<(BB * NF * NK + 255) / 256, 256, 0, stream>>>(ws, (float*)d_out);
}